// Round 6
// baseline (551.424 us; speedup 1.0000x reference)
//
#include <hip/hip_runtime.h>

// out[t, 0, d] = inputs[t, d]
// out[t, l, d] = memory[l, d]   (l = 1..L-1)
// T=2048, L=64, D=1024, fp32. Write-BW bound (512 MiB stores, ~8.3 MiB reads).
//
// R0: flat one-float4-per-thread, 131k WGs -> 539 us (best so far).
// R3/R4: grid-stride x32 -> ~571 us (regression).
// R5: 8-way ILP, stores spaced 64 MiB apart -> 551 us. Each wave kept 8
//   disjoint DRAM streams open — poor row-buffer locality.
// R6: 8-way ILP, BLOCK-CONTIGUOUS: each WG owns 2048 consecutive float4
//   (32 KiB), 8 stores per thread spaced 256 float4 (4 KiB). Wave-coalesced
//   AND DRAM-page local, matching the 6.3 TB/s rocclr fill's access shape.
//   Bench dur carries ~430 us fixed harness poison-fill overhead; deltas are
//   the signal.

typedef float floatx4 __attribute__((ext_vector_type(4)));

constexpr int T = 2048;
constexpr int L = 64;
constexpr int D = 1024;
constexpr int N4 = T * L * D / 4;          // 33,554,432 float4s
constexpr int UNROLL = 8;
constexpr int BLOCK = 256;
constexpr int CHUNK = UNROLL * BLOCK;      // 2048 float4 = 32 KiB per WG

__global__ __launch_bounds__(BLOCK) void sliding_window_memory_kernel(
    const floatx4* __restrict__ in,    // [T, D/4]   D/4 = 256
    const floatx4* __restrict__ mem,   // [L, D/4]   L*D/4 = 16384
    floatx4* __restrict__ out)         // [T, L, D/4]
{
    const int base = blockIdx.x * CHUNK + threadIdx.x;

    floatx4 v[UNROLL];
    #pragma unroll
    for (int k = 0; k < UNROLL; ++k) {
        const int i   = base + k * BLOCK;      // 8 consecutive 4 KiB rows
        const int rem = i & 16383;             // offset within [L, D/4] slab
        // wave-uniform per k: each k covers exactly one 256-float4 row
        if (rem < 256) v[k] = in[((i >> 14) << 8) + rem];  // l == 0
        else           v[k] = mem[rem];                    // frozen tail
    }

    #pragma unroll
    for (int k = 0; k < UNROLL; ++k)
        out[base + k * BLOCK] = v[k];          // contiguous 32 KiB per WG
}

extern "C" void kernel_launch(void* const* d_in, const int* in_sizes, int n_in,
                              void* d_out, int out_size, void* d_ws, size_t ws_size,
                              hipStream_t stream) {
    const floatx4* in  = (const floatx4*)d_in[0];   // inputs [T, D] fp32
    const floatx4* mem = (const floatx4*)d_in[1];   // memory [L, D] fp32
    floatx4* out = (floatx4*)d_out;                 // [T, L, D] fp32

    const int grid = N4 / CHUNK;                    // 16,384 WGs
    sliding_window_memory_kernel<<<grid, BLOCK, 0, stream>>>(in, mem, out);
}